// Round 2
// baseline (479.104 us; speedup 1.0000x reference)
//
#include <hip/hip_runtime.h>

#define BB 8
#define TT 128
#define EE 256
#define VV 8192
#define LL 5
#define NROWS (BB*TT)   // 1024

// x[b*T+t, :] = emb[idxs[b,t], :] + pos_emb[t, :]
__global__ void emb_kernel(const int* __restrict__ idxs, const float* __restrict__ emb,
                           const float* __restrict__ pos, float* __restrict__ x) {
    int row = blockIdx.x;            // b*T + t
    int h   = threadIdx.x;           // 0..255
    int t   = row % TT;
    int id  = idxs[row];
    x[row*EE + h] = emb[id*EE + h] + pos[t*EE + h];
}

// q,k,v = x @ Wq/Wk/Wv ; stored transposed [B, H, T] for coalesced attention loads
template<int R>
__global__ void qkv_kernel(const float* __restrict__ x,
                           const float* __restrict__ Wq, const float* __restrict__ Wk,
                           const float* __restrict__ Wv,
                           float* __restrict__ qt, float* __restrict__ kt, float* __restrict__ vt) {
    __shared__ float xs[R][EE];
    int h = threadIdx.x;
    int row0 = blockIdx.x * R;
    for (int r = 0; r < R; ++r) xs[r][h] = x[(row0 + r)*EE + h];
    __syncthreads();
    float aq[R], ak[R], av[R];
    #pragma unroll
    for (int r = 0; r < R; ++r) { aq[r] = 0.f; ak[r] = 0.f; av[r] = 0.f; }
    #pragma unroll 4
    for (int e = 0; e < EE; ++e) {
        float wq = Wq[e*EE + h];
        float wk = Wk[e*EE + h];
        float wv = Wv[e*EE + h];
        #pragma unroll
        for (int r = 0; r < R; ++r) {
            aq[r] += xs[r][e] * wq;
            ak[r] += xs[r][e] * wk;
            av[r] += xs[r][e] * wv;
        }
    }
    for (int r = 0; r < R; ++r) {
        int row = row0 + r;
        int b = row / TT, t = row % TT;
        int o = (b*EE + h)*TT + t;
        qt[o] = aq[r]; kt[o] = ak[r]; vt[o] = av[r];
    }
}

// scores[i,j] = q_i*k_j, mask j>i -> -inf, softmax over i (query axis!), out_i = sum_{j<=i} attn[i,j]*v_j
// x[b, i, h] += out_i
__global__ void attn_kernel(const float* __restrict__ qt, const float* __restrict__ kt,
                            const float* __restrict__ vt, float* __restrict__ x) {
    int bh = blockIdx.x;             // b*E + h
    int b = bh / EE, h = bh % EE;
    int t = threadIdx.x;             // 0..127
    __shared__ float qs[TT], ks[TT], vs[TT], ms[TT], rzs[TT];
    int base = bh * TT;
    qs[t] = qt[base + t];
    ks[t] = kt[base + t];
    vs[t] = vt[base + t];
    __syncthreads();
    // phase 1: per-column (j = t) softmax stats over i >= j
    float k = ks[t];
    float m = -INFINITY;
    for (int i = t; i < TT; ++i) m = fmaxf(m, qs[i] * k);
    float z = 0.f;
    for (int i = t; i < TT; ++i) z += __expf(qs[i] * k - m);
    ms[t] = m; rzs[t] = 1.f / z;
    __syncthreads();
    // phase 2: per-row (i = t) output
    float q = qs[t];
    float acc = 0.f;
    for (int j = 0; j <= t; ++j)
        acc += __expf(q * ks[j] - ms[j]) * rzs[j] * vs[j];
    x[(b*TT + t)*EE + h] += acc;
}

// x += relu(x @ Wfc + bfc)   (in-place; block reads its rows into LDS first)
template<int R>
__global__ void fc_kernel(float* __restrict__ x, const float* __restrict__ Wfc,
                          const float* __restrict__ bfc) {
    __shared__ float xs[R][EE];
    int h = threadIdx.x;
    int row0 = blockIdx.x * R;
    for (int r = 0; r < R; ++r) xs[r][h] = x[(row0 + r)*EE + h];
    __syncthreads();
    float acc[R];
    float bias = bfc[h];
    #pragma unroll
    for (int r = 0; r < R; ++r) acc[r] = bias;
    #pragma unroll 4
    for (int e = 0; e < EE; ++e) {
        float w = Wfc[e*EE + h];
        #pragma unroll
        for (int r = 0; r < R; ++r) acc[r] += xs[r][e] * w;
    }
    for (int r = 0; r < R; ++r)
        x[(row0 + r)*EE + h] += fmaxf(acc[r], 0.f);
}

// logits[r, v] = x[r,:] @ Wlm[:,v] + blm[v]
template<int R>
__global__ void lm_kernel(const float* __restrict__ x, const float* __restrict__ Wlm,
                          const float* __restrict__ blm, float* __restrict__ out) {
    __shared__ float xs[R][EE];
    int v = blockIdx.x * 256 + threadIdx.x;
    int row0 = blockIdx.y * R;
    for (int r = 0; r < R; ++r) xs[r][threadIdx.x] = x[(row0 + r)*EE + threadIdx.x];
    __syncthreads();
    float acc[R];
    float bias = blm[v];
    #pragma unroll
    for (int r = 0; r < R; ++r) acc[r] = bias;
    #pragma unroll 4
    for (int e = 0; e < EE; ++e) {
        float w = Wlm[e*VV + v];
        #pragma unroll
        for (int r = 0; r < R; ++r) acc[r] += xs[r][e] * w;
    }
    for (int r = 0; r < R; ++r)
        out[(size_t)(row0 + r)*VV + v] = acc[r];
}

// per-row: lse - logit[target]
__global__ void loss_row_kernel(const float* __restrict__ logits, const int* __restrict__ targets,
                                float* __restrict__ row_loss) {
    int r = blockIdx.x;
    int tid = threadIdx.x;           // 256
    const float* row = logits + (size_t)r * VV;
    __shared__ float red[256];
    float m = -INFINITY;
    for (int v = tid; v < VV; v += 256) m = fmaxf(m, row[v]);
    red[tid] = m; __syncthreads();
    for (int s = 128; s > 0; s >>= 1) {
        if (tid < s) red[tid] = fmaxf(red[tid], red[tid + s]);
        __syncthreads();
    }
    m = red[0]; __syncthreads();
    float z = 0.f;
    for (int v = tid; v < VV; v += 256) z += __expf(row[v] - m);
    red[tid] = z; __syncthreads();
    for (int s = 128; s > 0; s >>= 1) {
        if (tid < s) red[tid] += red[tid + s];
        __syncthreads();
    }
    if (tid == 0) {
        float lse = m + logf(red[0]);
        float tgt = row[targets[r]];
        row_loss[r] = lse - tgt;
    }
}

__global__ void loss_final_kernel(const float* __restrict__ row_loss, float* __restrict__ out) {
    int tid = threadIdx.x;           // 256
    __shared__ float red[256];
    float s = 0.f;
    for (int r = tid; r < NROWS; r += 256) s += row_loss[r];
    red[tid] = s; __syncthreads();
    for (int k = 128; k > 0; k >>= 1) {
        if (tid < k) red[tid] += red[tid + k];
        __syncthreads();
    }
    if (tid == 0) out[(size_t)NROWS * VV] = red[0] / NROWS;
}

extern "C" void kernel_launch(void* const* d_in, const int* in_sizes, int n_in,
                              void* d_out, int out_size, void* d_ws, size_t ws_size,
                              hipStream_t stream) {
    const int*   idxs    = (const int*)d_in[0];
    const int*   targets = (const int*)d_in[1];
    const float* emb     = (const float*)d_in[2];
    const float* pos     = (const float*)d_in[3];
    const float* Wq      = (const float*)d_in[4];
    const float* Wk      = (const float*)d_in[5];
    const float* Wv      = (const float*)d_in[6];
    const float* Wfc     = (const float*)d_in[7];
    const float* bfc     = (const float*)d_in[8];
    const float* Wlm     = (const float*)d_in[9];
    const float* blm     = (const float*)d_in[10];
    float* out = (float*)d_out;

    float* ws = (float*)d_ws;
    float* x        = ws;                          // [1024, 256]
    float* qt       = x  + NROWS*EE;               // [B, H, T]
    float* kt       = qt + NROWS*EE;
    float* vt       = kt + NROWS*EE;
    float* row_loss = vt + NROWS*EE;               // [1024]

    emb_kernel<<<NROWS, EE, 0, stream>>>(idxs, emb, pos, x);

    for (int l = 0; l < LL; ++l) {
        qkv_kernel<4><<<NROWS/4, EE, 0, stream>>>(x, Wq + l*EE*EE, Wk + l*EE*EE, Wv + l*EE*EE,
                                                  qt, kt, vt);
        attn_kernel<<<BB*EE, TT, 0, stream>>>(qt, kt, vt, x);
        fc_kernel<4><<<NROWS/4, EE, 0, stream>>>(x, Wfc + l*EE*EE, bfc + l*EE);
    }

    lm_kernel<16><<<dim3(VV/256, NROWS/16), 256, 0, stream>>>(x, Wlm, blm, out);
    loss_row_kernel<<<NROWS, 256, 0, stream>>>(out, targets, row_loss);
    loss_final_kernel<<<1, 256, 0, stream>>>(row_loss, out);
}

// Round 3
// 305.481 us; speedup vs baseline: 1.5684x; 1.5684x over previous
//
#include <hip/hip_runtime.h>

#define BB 8
#define TT 128
#define EE 256
#define VV 8192
#define LL 5
#define NROWS (BB*TT)   // 1024

typedef __attribute__((ext_vector_type(8))) short bf16x8;
typedef __attribute__((ext_vector_type(4))) float f32x4;

__device__ inline ushort f2bf(float f) {
    union { float f; unsigned u; } c; c.f = f;
    unsigned u = c.u;
    return (ushort)((u + 0x7FFF + ((u >> 16) & 1)) >> 16);  // RNE
}

// x[b*T+t, :] = emb[idxs[b,t], :] + pos_emb[t, :]
__global__ void emb_kernel(const int* __restrict__ idxs, const float* __restrict__ emb,
                           const float* __restrict__ pos, float* __restrict__ x) {
    int row = blockIdx.x;
    int h   = threadIdx.x;
    int t   = row % TT;
    int id  = idxs[row];
    x[row*EE + h] = emb[id*EE + h] + pos[t*EE + h];
}

// q|k|v (selected by blockIdx.y) = x @ W ; stored transposed [B, H, T]
template<int R>
__global__ void qkv_kernel(const float* __restrict__ x,
                           const float* __restrict__ Wq, const float* __restrict__ Wk,
                           const float* __restrict__ Wv,
                           float* __restrict__ qt, float* __restrict__ kt, float* __restrict__ vt) {
    __shared__ float xs[R][EE];
    int h = threadIdx.x;
    int row0 = blockIdx.x * R;
    const float* W = (blockIdx.y == 0) ? Wq : (blockIdx.y == 1 ? Wk : Wv);
    float*       o = (blockIdx.y == 0) ? qt : (blockIdx.y == 1 ? kt : vt);
    for (int r = 0; r < R; ++r) xs[r][h] = x[(row0 + r)*EE + h];
    __syncthreads();
    float a[R];
    #pragma unroll
    for (int r = 0; r < R; ++r) a[r] = 0.f;
    #pragma unroll 8
    for (int e = 0; e < EE; ++e) {
        float w = W[e*EE + h];
        #pragma unroll
        for (int r = 0; r < R; ++r) a[r] += xs[r][e] * w;
    }
    for (int r = 0; r < R; ++r) {
        int row = row0 + r;
        int b = row / TT, t = row % TT;
        o[(b*EE + h)*TT + t] = a[r];
    }
}

// scores[i,j]=q_i*k_j, mask j>i, softmax over i (query axis), out_i = sum_{j<=i} attn*v_j
__global__ void attn_kernel(const float* __restrict__ qt, const float* __restrict__ kt,
                            const float* __restrict__ vt, float* __restrict__ x) {
    int bh = blockIdx.x;             // b*E + h
    int b = bh / EE, h = bh % EE;
    int t = threadIdx.x;             // 0..127
    __shared__ float qs[TT], ks[TT], vs[TT], ms[TT], rzs[TT];
    int base = bh * TT;
    qs[t] = qt[base + t];
    ks[t] = kt[base + t];
    vs[t] = vt[base + t];
    __syncthreads();
    float k = ks[t];
    float m = -INFINITY;
    for (int i = t; i < TT; ++i) m = fmaxf(m, qs[i] * k);
    float z = 0.f;
    for (int i = t; i < TT; ++i) z += __expf(qs[i] * k - m);
    ms[t] = m; rzs[t] = 1.f / z;
    __syncthreads();
    float q = qs[t];
    float acc = 0.f;
    for (int j = 0; j <= t; ++j)
        acc += __expf(q * ks[j] - ms[j]) * rzs[j] * vs[j];
    x[(b*TT + t)*EE + h] += acc;
}

// x += relu(x @ Wfc + bfc)
template<int R>
__global__ void fc_kernel(float* __restrict__ x, const float* __restrict__ Wfc,
                          const float* __restrict__ bfc) {
    __shared__ float xs[R][EE];
    int h = threadIdx.x;
    int row0 = blockIdx.x * R;
    for (int r = 0; r < R; ++r) xs[r][h] = x[(row0 + r)*EE + h];
    __syncthreads();
    float acc[R];
    float bias = bfc[h];
    #pragma unroll
    for (int r = 0; r < R; ++r) acc[r] = bias;
    #pragma unroll 8
    for (int e = 0; e < EE; ++e) {
        float w = Wfc[e*EE + h];
        #pragma unroll
        for (int r = 0; r < R; ++r) acc[r] += xs[r][e] * w;
    }
    for (int r = 0; r < R; ++r)
        x[(row0 + r)*EE + h] += fmaxf(acc[r], 0.f);
}

// Wlm [256][8192] f32 -> WlmT [8192][256] bf16 (64x64 tiles via LDS)
__global__ void wlmT_kernel(const float* __restrict__ Wlm, ushort* __restrict__ WlmT) {
    __shared__ ushort ts[64][72];
    int v0 = blockIdx.x * 64, k0 = blockIdx.y * 64;
    int lane = threadIdx.x & 63, w = threadIdx.x >> 6;
    for (int kk = w; kk < 64; kk += 4)
        ts[lane][kk] = f2bf(Wlm[(size_t)(k0 + kk)*VV + v0 + lane]);
    __syncthreads();
    for (int vv = w; vv < 64; vv += 4)
        WlmT[(size_t)(v0 + vv)*EE + k0 + lane] = ts[vv][lane];
}

// logits = x @ Wlm + blm via bf16 MFMA; fused per-(row,colblock) softmax partials.
// block: 64 rows x 64 cols, 4 waves (wave w = rows w*16..w*16+15), K=256.
__global__ __launch_bounds__(256) void lm_mfma_kernel(
        const float* __restrict__ x, const ushort* __restrict__ WlmT,
        const float* __restrict__ blm, float* __restrict__ out,
        float* __restrict__ pm, float* __restrict__ pz) {
    __shared__ ushort As[64*256];
    __shared__ ushort Bs[64*256];
    int tid = threadIdx.x;
    int lane = tid & 63, w = tid >> 6;
    int c0 = blockIdx.x * 64;      // vocab base
    int r0 = blockIdx.y * 64;      // row base

    // stage A: wave reads one full row (64 lanes x float4 = 1KB) per iter
    for (int rr = w; rr < 64; rr += 4) {
        float4 v = *(const float4*)&x[(size_t)(r0 + rr)*EE + lane*4];
        ushort4 h;
        h.x = f2bf(v.x); h.y = f2bf(v.y); h.z = f2bf(v.z); h.w = f2bf(v.w);
        *(ushort4*)&As[rr*256 + ((lane*4) ^ ((rr & 7) << 3))] = h;
    }
    // stage B: 2 cols per wave-instr (32 lanes x 16B = 512B = one col of WlmT)
    for (int it = 0; it < 8; ++it) {
        int c = w*16 + (lane >> 5) + 2*it;
        int k0i = (lane & 31) * 8;
        uint4 v = *(const uint4*)&WlmT[(size_t)(c0 + c)*EE + k0i];
        *(uint4*)&Bs[c*256 + (k0i ^ ((c & 7) << 3))] = v;
    }
    __syncthreads();

    f32x4 acc[4] = {};
    int rband = w*16 + (lane & 15);
    int kq = (lane >> 4) * 8;
    for (int ks = 0; ks < 8; ++ks) {
        int kk = ks*32 + kq;
        bf16x8 a = *(const bf16x8*)&As[rband*256 + (kk ^ ((rband & 7) << 3))];
        #pragma unroll
        for (int n = 0; n < 4; ++n) {
            int c = n*16 + (lane & 15);
            bf16x8 b = *(const bf16x8*)&Bs[c*256 + (kk ^ ((c & 7) << 3))];
            acc[n] = __builtin_amdgcn_mfma_f32_16x16x32_bf16(a, b, acc[n], 0, 0, 0);
        }
    }

    // epilogue: bias, store, per-row (max, expsum) over this 64-col block
    float bias[4];
    #pragma unroll
    for (int n = 0; n < 4; ++n) bias[n] = blm[c0 + n*16 + (lane & 15)];
    int rowg = r0 + w*16 + (lane >> 4)*4;
    #pragma unroll
    for (int j = 0; j < 4; ++j) {
        float vals[4];
        float vmax = -INFINITY;
        #pragma unroll
        for (int n = 0; n < 4; ++n) {
            vals[n] = acc[n][j] + bias[n];
            out[(size_t)(rowg + j)*VV + c0 + n*16 + (lane & 15)] = vals[n];
            vmax = fmaxf(vmax, vals[n]);
        }
        #pragma unroll
        for (int m = 1; m <= 8; m <<= 1) vmax = fmaxf(vmax, __shfl_xor(vmax, m));
        float z = 0.f;
        #pragma unroll
        for (int n = 0; n < 4; ++n) z += __expf(vals[n] - vmax);
        #pragma unroll
        for (int m = 1; m <= 8; m <<= 1) z += __shfl_xor(z, m);
        if ((lane & 15) == 0) {
            pm[(size_t)(rowg + j)*128 + blockIdx.x] = vmax;
            pz[(size_t)(rowg + j)*128 + blockIdx.x] = z;
        }
    }
}

// combine 128 (m,z) partials per row -> row_loss
__global__ void loss_reduce_kernel(const float* __restrict__ pm, const float* __restrict__ pz,
                                   const float* __restrict__ logits, const int* __restrict__ targets,
                                   float* __restrict__ row_loss) {
    int r = blockIdx.x;
    int t = threadIdx.x;             // 128
    __shared__ float sm[128], sz[128];
    float m = pm[(size_t)r*128 + t];
    float z = pz[(size_t)r*128 + t];
    sm[t] = m; __syncthreads();
    for (int s = 64; s > 0; s >>= 1) {
        if (t < s) sm[t] = fmaxf(sm[t], sm[t + s]);
        __syncthreads();
    }
    float M = sm[0];
    sz[t] = z * __expf(m - M); __syncthreads();
    for (int s = 64; s > 0; s >>= 1) {
        if (t < s) sz[t] += sz[t + s];
        __syncthreads();
    }
    if (t == 0) {
        float lse = M + logf(sz[0]);
        row_loss[r] = lse - logits[(size_t)r*VV + targets[r]];
    }
}

__global__ void loss_final_kernel(const float* __restrict__ row_loss, float* __restrict__ out) {
    int tid = threadIdx.x;           // 256
    __shared__ float red[256];
    float s = 0.f;
    for (int r = tid; r < NROWS; r += 256) s += row_loss[r];
    red[tid] = s; __syncthreads();
    for (int k = 128; k > 0; k >>= 1) {
        if (tid < k) red[tid] += red[tid + k];
        __syncthreads();
    }
    if (tid == 0) out[(size_t)NROWS * VV] = red[0] / NROWS;
}

extern "C" void kernel_launch(void* const* d_in, const int* in_sizes, int n_in,
                              void* d_out, int out_size, void* d_ws, size_t ws_size,
                              hipStream_t stream) {
    const int*   idxs    = (const int*)d_in[0];
    const int*   targets = (const int*)d_in[1];
    const float* emb     = (const float*)d_in[2];
    const float* pos     = (const float*)d_in[3];
    const float* Wq      = (const float*)d_in[4];
    const float* Wk      = (const float*)d_in[5];
    const float* Wv      = (const float*)d_in[6];
    const float* Wfc     = (const float*)d_in[7];
    const float* bfc     = (const float*)d_in[8];
    const float* Wlm     = (const float*)d_in[9];
    const float* blm     = (const float*)d_in[10];
    float* out = (float*)d_out;

    float* ws = (float*)d_ws;
    float* x        = ws;                          // 262144
    float* qt       = x  + NROWS*EE;
    float* kt       = qt + NROWS*EE;
    float* vt       = kt + NROWS*EE;
    float* row_loss = vt + NROWS*EE;               // 1024
    float* pm       = row_loss + 1024;             // 1024*128
    float* pz       = pm + NROWS*128;              // 1024*128
    ushort* WlmT    = (ushort*)(pz + NROWS*128);   // 8192*256 bf16

    wlmT_kernel<<<dim3(VV/64, EE/64), 256, 0, stream>>>(Wlm, WlmT);
    emb_kernel<<<NROWS, EE, 0, stream>>>(idxs, emb, pos, x);

    for (int l = 0; l < LL; ++l) {
        qkv_kernel<4><<<dim3(NROWS/4, 3), EE, 0, stream>>>(x, Wq + l*EE*EE, Wk + l*EE*EE,
                                                           Wv + l*EE*EE, qt, kt, vt);
        attn_kernel<<<BB*EE, TT, 0, stream>>>(qt, kt, vt, x);
        fc_kernel<2><<<NROWS/2, EE, 0, stream>>>(x, Wfc + l*EE*EE, bfc + l*EE);
    }

    lm_mfma_kernel<<<dim3(VV/64, NROWS/64), 256, 0, stream>>>(x, WlmT, blm, out, pm, pz);
    loss_reduce_kernel<<<NROWS, 128, 0, stream>>>(pm, pz, out, targets, row_loss);
    loss_final_kernel<<<1, 256, 0, stream>>>(row_loss, out);
}

// Round 4
// 253.145 us; speedup vs baseline: 1.8926x; 1.2067x over previous
//
#include <hip/hip_runtime.h>

#define BB 8
#define TT 128
#define EE 256
#define VV 8192
#define LL 5
#define NROWS (BB*TT)   // 1024

typedef __attribute__((ext_vector_type(8))) short bf16x8;
typedef __attribute__((ext_vector_type(4))) float f32x4;

__device__ inline ushort f2bf(float f) {
    union { float f; unsigned u; } c; c.f = f;
    unsigned u = c.u;
    return (ushort)((u + 0x7FFF + ((u >> 16) & 1)) >> 16);  // RNE
}

// ---------------- prep: loss-cell zero + WlmT + per-layer weight transposes + embedding ----
// id 0: zero loss cell
// id [1,513): WlmT tiles (Wlm [256][8192] f32 -> [8192][256] bf16)
// id [513,833): 20 mats [256][256] -> transposed bf16, mat = l*4 + {q,k,v,fc}
// id [833,1089): embedding, 4 rows per block
__global__ __launch_bounds__(256) void prep_kernel(
        const int* __restrict__ idxs, const float* __restrict__ emb, const float* __restrict__ pos,
        const float* __restrict__ Wq, const float* __restrict__ Wk,
        const float* __restrict__ Wv, const float* __restrict__ Wfc,
        const float* __restrict__ Wlm,
        float* __restrict__ x0, ushort* __restrict__ WTs, ushort* __restrict__ WlmT,
        float* __restrict__ loss_cell) {
    int id = blockIdx.x;
    if (id == 0) {
        if (threadIdx.x == 0) *loss_cell = 0.f;
        return;
    }
    if (id < 513) {
        int idw = id - 1;
        int v0 = (idw & 127) * 64, k0 = (idw >> 7) * 64;
        __shared__ ushort ts[64][72];
        int lane = threadIdx.x & 63, w = threadIdx.x >> 6;
        for (int kk = w; kk < 64; kk += 4)
            ts[lane][kk] = f2bf(Wlm[(size_t)(k0 + kk)*VV + v0 + lane]);
        __syncthreads();
        for (int vv = w; vv < 64; vv += 4)
            WlmT[(size_t)(v0 + vv)*EE + k0 + lane] = ts[vv][lane];
        return;
    }
    if (id < 833) {
        int idm = id - 513;
        int mat = idm >> 4, tile = idm & 15;
        int l = mat >> 2, type = mat & 3;
        const float* src = (type == 0 ? Wq : type == 1 ? Wk : type == 2 ? Wv : Wfc) + l*EE*EE;
        ushort* dst = WTs + mat*EE*EE;
        int i0 = (tile >> 2) * 64, o0 = (tile & 3) * 64;
        __shared__ ushort ts[64][72];
        int lane = threadIdx.x & 63, w = threadIdx.x >> 6;
        for (int ii = w; ii < 64; ii += 4)
            ts[lane][ii] = f2bf(src[(i0 + ii)*EE + o0 + lane]);
        __syncthreads();
        for (int oo = w; oo < 64; oo += 4)
            dst[(o0 + oo)*EE + i0 + lane] = ts[oo][lane];
        return;
    }
    int h = threadIdx.x;
    int row0 = (id - 833) * 4;
    for (int r = 0; r < 4; ++r) {
        int row = row0 + r;
        x0[row*EE + h] = emb[(size_t)idxs[row]*EE + h] + pos[(row & (TT-1))*EE + h];
    }
}

// ---------------- q,k,v = x @ W (3 GEMMs fused along grid.x), transposed f32 stores [B,H,T]
// block: 64 rows x 64 cols, 4 waves, K=256. grid (12, 16).
__global__ __launch_bounds__(256) void qkv_mfma(
        const float* __restrict__ xin, const ushort* __restrict__ WTl,
        float* __restrict__ qt, float* __restrict__ kt, float* __restrict__ vt) {
    __shared__ ushort As[64*256];
    __shared__ ushort Bs[64*256];
    int tid = threadIdx.x, lane = tid & 63, w = tid >> 6;
    int mat = blockIdx.x >> 2;
    int c0 = (blockIdx.x & 3) * 64;
    int r0 = blockIdx.y * 64;
    const ushort* WT = WTl + mat*EE*EE;
    float* o = mat == 0 ? qt : (mat == 1 ? kt : vt);

    for (int rr = w; rr < 64; rr += 4) {
        float4 v = *(const float4*)&xin[(size_t)(r0 + rr)*EE + lane*4];
        ushort4 hh; hh.x = f2bf(v.x); hh.y = f2bf(v.y); hh.z = f2bf(v.z); hh.w = f2bf(v.w);
        *(ushort4*)&As[rr*256 + ((lane*4) ^ ((rr & 7) << 3))] = hh;
    }
    for (int it = 0; it < 8; ++it) {
        int c = w*16 + (lane >> 5) + 2*it;
        int k0i = (lane & 31) * 8;
        uint4 v = *(const uint4*)&WT[(size_t)(c0 + c)*EE + k0i];
        *(uint4*)&Bs[c*256 + (k0i ^ ((c & 7) << 3))] = v;
    }
    __syncthreads();

    f32x4 acc[4] = {};
    int rband = w*16 + (lane & 15);
    int kq = (lane >> 4) * 8;
    for (int ks = 0; ks < 8; ++ks) {
        int kk = ks*32 + kq;
        bf16x8 a = *(const bf16x8*)&As[rband*256 + (kk ^ ((rband & 7) << 3))];
        #pragma unroll
        for (int n = 0; n < 4; ++n) {
            int c = n*16 + (lane & 15);
            bf16x8 b = *(const bf16x8*)&Bs[c*256 + (kk ^ ((c & 7) << 3))];
            acc[n] = __builtin_amdgcn_mfma_f32_16x16x32_bf16(a, b, acc[n], 0, 0, 0);
        }
    }
    int grow0 = r0 + w*16 + ((lane >> 4) << 2);
    int b = grow0 >> 7, t0 = grow0 & (TT-1);
    #pragma unroll
    for (int n = 0; n < 4; ++n) {
        int h = c0 + n*16 + (lane & 15);
        float4 vv = make_float4(acc[n][0], acc[n][1], acc[n][2], acc[n][3]);
        *(float4*)&o[((size_t)(b*EE + h))*TT + t0] = vv;
    }
}

// ---------------- attention (2 heads per 256-thr block), x += out
__global__ __launch_bounds__(256) void attn_kernel(
        const float* __restrict__ qt, const float* __restrict__ kt,
        const float* __restrict__ vt, float* __restrict__ x) {
    int pair = threadIdx.x >> 7;
    int t = threadIdx.x & (TT-1);
    int bh = blockIdx.x*2 + pair;
    int b = bh >> 8, h = bh & 255;
    __shared__ float qs[2][TT], ks[2][TT], vs[2][TT], ms[2][TT], rzs[2][TT];
    int base = bh * TT;
    qs[pair][t] = qt[base + t];
    ks[pair][t] = kt[base + t];
    vs[pair][t] = vt[base + t];
    __syncthreads();
    float k = ks[pair][t];
    float m = -INFINITY;
    for (int i = t; i < TT; ++i) m = fmaxf(m, qs[pair][i] * k);
    float z = 0.f;
    for (int i = t; i < TT; ++i) z += __expf(qs[pair][i] * k - m);
    ms[pair][t] = m; rzs[pair][t] = 1.f / z;
    __syncthreads();
    float q = qs[pair][t];
    float acc = 0.f;
    for (int j = 0; j <= t; ++j)
        acc += __expf(q * ks[pair][j] - ms[pair][j]) * rzs[pair][j] * vs[pair][j];
    x[(size_t)(b*TT + t)*EE + h] += acc;
}

// ---------------- xout = xin + relu(xin @ Wfc + bfc). grid (4, 16).
__global__ __launch_bounds__(256) void fc_mfma(
        const float* __restrict__ xin, const ushort* __restrict__ WT,
        const float* __restrict__ bfc, float* __restrict__ xout) {
    __shared__ ushort As[64*256];
    __shared__ ushort Bs[64*256];
    int tid = threadIdx.x, lane = tid & 63, w = tid >> 6;
    int c0 = blockIdx.x * 64;
    int r0 = blockIdx.y * 64;

    for (int rr = w; rr < 64; rr += 4) {
        float4 v = *(const float4*)&xin[(size_t)(r0 + rr)*EE + lane*4];
        ushort4 hh; hh.x = f2bf(v.x); hh.y = f2bf(v.y); hh.z = f2bf(v.z); hh.w = f2bf(v.w);
        *(ushort4*)&As[rr*256 + ((lane*4) ^ ((rr & 7) << 3))] = hh;
    }
    for (int it = 0; it < 8; ++it) {
        int c = w*16 + (lane >> 5) + 2*it;
        int k0i = (lane & 31) * 8;
        uint4 v = *(const uint4*)&WT[(size_t)(c0 + c)*EE + k0i];
        *(uint4*)&Bs[c*256 + (k0i ^ ((c & 7) << 3))] = v;
    }
    __syncthreads();

    f32x4 acc[4] = {};
    int rband = w*16 + (lane & 15);
    int kq = (lane >> 4) * 8;
    for (int ks = 0; ks < 8; ++ks) {
        int kk = ks*32 + kq;
        bf16x8 a = *(const bf16x8*)&As[rband*256 + (kk ^ ((rband & 7) << 3))];
        #pragma unroll
        for (int n = 0; n < 4; ++n) {
            int c = n*16 + (lane & 15);
            bf16x8 b = *(const bf16x8*)&Bs[c*256 + (kk ^ ((c & 7) << 3))];
            acc[n] = __builtin_amdgcn_mfma_f32_16x16x32_bf16(a, b, acc[n], 0, 0, 0);
        }
    }
    int grow0 = r0 + w*16 + ((lane >> 4) << 2);
    #pragma unroll
    for (int n = 0; n < 4; ++n) {
        int col = c0 + n*16 + (lane & 15);
        float bias = bfc[col];
        #pragma unroll
        for (int j = 0; j < 4; ++j) {
            size_t idx = (size_t)(grow0 + j)*EE + col;
            xout[idx] = xin[idx] + fmaxf(acc[n][j] + bias, 0.f);
        }
    }
}

// ---------------- logits = x @ Wlm + blm (MFMA) + fused per-(row,64col) softmax partials
__global__ __launch_bounds__(256) void lm_mfma_kernel(
        const float* __restrict__ x, const ushort* __restrict__ WlmT,
        const float* __restrict__ blm, float* __restrict__ out,
        float* __restrict__ pm, float* __restrict__ pz) {
    __shared__ ushort As[64*256];
    __shared__ ushort Bs[64*256];
    int tid = threadIdx.x;
    int lane = tid & 63, w = tid >> 6;
    int c0 = blockIdx.x * 64;
    int r0 = blockIdx.y * 64;

    for (int rr = w; rr < 64; rr += 4) {
        float4 v = *(const float4*)&x[(size_t)(r0 + rr)*EE + lane*4];
        ushort4 hh; hh.x = f2bf(v.x); hh.y = f2bf(v.y); hh.z = f2bf(v.z); hh.w = f2bf(v.w);
        *(ushort4*)&As[rr*256 + ((lane*4) ^ ((rr & 7) << 3))] = hh;
    }
    for (int it = 0; it < 8; ++it) {
        int c = w*16 + (lane >> 5) + 2*it;
        int k0i = (lane & 31) * 8;
        uint4 v = *(const uint4*)&WlmT[(size_t)(c0 + c)*EE + k0i];
        *(uint4*)&Bs[c*256 + (k0i ^ ((c & 7) << 3))] = v;
    }
    __syncthreads();

    f32x4 acc[4] = {};
    int rband = w*16 + (lane & 15);
    int kq = (lane >> 4) * 8;
    for (int ks = 0; ks < 8; ++ks) {
        int kk = ks*32 + kq;
        bf16x8 a = *(const bf16x8*)&As[rband*256 + (kk ^ ((rband & 7) << 3))];
        #pragma unroll
        for (int n = 0; n < 4; ++n) {
            int c = n*16 + (lane & 15);
            bf16x8 b = *(const bf16x8*)&Bs[c*256 + (kk ^ ((c & 7) << 3))];
            acc[n] = __builtin_amdgcn_mfma_f32_16x16x32_bf16(a, b, acc[n], 0, 0, 0);
        }
    }

    float bias[4];
    #pragma unroll
    for (int n = 0; n < 4; ++n) bias[n] = blm[c0 + n*16 + (lane & 15)];
    int rowg = r0 + w*16 + (lane >> 4)*4;
    #pragma unroll
    for (int j = 0; j < 4; ++j) {
        float vals[4];
        float vmax = -INFINITY;
        #pragma unroll
        for (int n = 0; n < 4; ++n) {
            vals[n] = acc[n][j] + bias[n];
            out[(size_t)(rowg + j)*VV + c0 + n*16 + (lane & 15)] = vals[n];
            vmax = fmaxf(vmax, vals[n]);
        }
        #pragma unroll
        for (int m = 1; m <= 8; m <<= 1) vmax = fmaxf(vmax, __shfl_xor(vmax, m));
        float z = 0.f;
        #pragma unroll
        for (int n = 0; n < 4; ++n) z += __expf(vals[n] - vmax);
        #pragma unroll
        for (int m = 1; m <= 8; m <<= 1) z += __shfl_xor(z, m);
        if ((lane & 15) == 0) {
            pm[(size_t)(rowg + j)*128 + blockIdx.x] = vmax;
            pz[(size_t)(rowg + j)*128 + blockIdx.x] = z;
        }
    }
}

// ---------------- per-row loss from partials, atomicAdd mean into pre-zeroed loss cell
__global__ void loss_kernel(const float* __restrict__ pm, const float* __restrict__ pz,
                            const float* __restrict__ logits, const int* __restrict__ targets,
                            float* __restrict__ out_last) {
    int r = blockIdx.x;
    int t = threadIdx.x;             // 128
    __shared__ float sm[128], sz[128];
    float m = pm[(size_t)r*128 + t];
    float z = pz[(size_t)r*128 + t];
    sm[t] = m; __syncthreads();
    for (int s = 64; s > 0; s >>= 1) {
        if (t < s) sm[t] = fmaxf(sm[t], sm[t + s]);
        __syncthreads();
    }
    float M = sm[0];
    sz[t] = z * __expf(m - M); __syncthreads();
    for (int s = 64; s > 0; s >>= 1) {
        if (t < s) sz[t] += sz[t + s];
        __syncthreads();
    }
    if (t == 0) {
        float lse = M + logf(sz[0]);
        atomicAdd(out_last, (lse - logits[(size_t)r*VV + targets[r]]) * (1.0f / NROWS));
    }
}

extern "C" void kernel_launch(void* const* d_in, const int* in_sizes, int n_in,
                              void* d_out, int out_size, void* d_ws, size_t ws_size,
                              hipStream_t stream) {
    const int*   idxs    = (const int*)d_in[0];
    const int*   targets = (const int*)d_in[1];
    const float* emb     = (const float*)d_in[2];
    const float* pos     = (const float*)d_in[3];
    const float* Wq      = (const float*)d_in[4];
    const float* Wk      = (const float*)d_in[5];
    const float* Wv      = (const float*)d_in[6];
    const float* Wfc     = (const float*)d_in[7];
    const float* bfc     = (const float*)d_in[8];
    const float* Wlm     = (const float*)d_in[9];
    const float* blm     = (const float*)d_in[10];
    float* out = (float*)d_out;
    float* loss_cell = out + (size_t)NROWS * VV;

    float* ws = (float*)d_ws;
    float*  xa   = ws;                       // [1024,256]
    float*  xb   = xa + NROWS*EE;
    float*  qt   = xb + NROWS*EE;            // [B,H,T]
    float*  kt   = qt + NROWS*EE;
    float*  vt   = kt + NROWS*EE;
    float*  pm   = vt + NROWS*EE;            // [1024,128]
    float*  pz   = pm + NROWS*128;
    ushort* WTs  = (ushort*)(pz + NROWS*128);   // 20 * 256*256 bf16
    ushort* WlmT = WTs + 20*EE*EE;              // 8192*256 bf16

    prep_kernel<<<1089, 256, 0, stream>>>(idxs, emb, pos, Wq, Wk, Wv, Wfc, Wlm,
                                          xa, WTs, WlmT, loss_cell);

    for (int l = 0; l < LL; ++l) {
        float* xi = (l & 1) ? xb : xa;
        float* xo = (l & 1) ? xa : xb;
        qkv_mfma<<<dim3(12, 16), 256, 0, stream>>>(xi, WTs + (size_t)l*4*EE*EE, qt, kt, vt);
        attn_kernel<<<1024, 256, 0, stream>>>(qt, kt, vt, xi);
        fc_mfma<<<dim3(4, 16), 256, 0, stream>>>(xi, WTs + (size_t)(l*4 + 3)*EE*EE,
                                                 bfc + l*EE, xo);
    }

    lm_mfma_kernel<<<dim3(VV/64, NROWS/64), 256, 0, stream>>>(xb, WlmT, blm, out, pm, pz);
    loss_kernel<<<NROWS, 128, 0, stream>>>(pm, pz, out, targets, loss_cell);
}